// Round 4
// baseline (244.088 us; speedup 1.0000x reference)
//
#include <hip/hip_runtime.h>
#include <math.h>

#define BB 256
#define SS 256
#define NH 4

typedef __attribute__((ext_vector_type(8))) short bfrag;   // 8 bf16 (4 VGPRs)
typedef __attribute__((ext_vector_type(4))) float ffrag;   // 4 fp32 acc

__device__ inline unsigned short f2bf(float x) {
    unsigned u = __float_as_uint(x);
    u += 0x7FFF + ((u >> 16) & 1);          // round-to-nearest-even
    return (unsigned short)(u >> 16);
}
__device__ inline float bf2f(unsigned short h) {
    return __uint_as_float(((unsigned)h) << 16);
}
__device__ inline unsigned pack2(float a, float b) {
    return (unsigned)f2bf(a) | ((unsigned)f2bf(b) << 16);
}
union FragU { unsigned u[4]; bfrag b; };

// ws layout (bf16 elements):
//   Xb  at 0         [B][S][128]   8388608
//   Wb  at 8388608   [512][128]      65536
//   Wob at 8454144   [128][128]      16384
//   ogT at 8470528   [S][B][128]   8388608   (transposed for k3 coalescing)
#define XB_OFF  0
#define WB_OFF  8388608
#define WOB_OFF 8454144
#define OG_OFF  8470528

// ---------------------------------------------------------------------------
// k0: cast X, W_qkvg, W_o from fp32 to bf16 into workspace. 8 elems/thread.
// ---------------------------------------------------------------------------
__global__ __launch_bounds__(256) void k0_cast(
    const float* __restrict__ X, const float* __restrict__ W,
    const float* __restrict__ Wo, unsigned short* __restrict__ dst)
{
    const int gid = blockIdx.x * 256 + threadIdx.x;
    const int XN8 = 8388608 / 8, WN8 = 65536 / 8, WoN8 = 16384 / 8;
    const float* src;
    size_t soff, doff;
    if (gid < XN8)            { src = X;  soff = (size_t)gid * 8;                 doff = XB_OFF + soff; }
    else if (gid < XN8 + WN8) { src = W;  soff = (size_t)(gid - XN8) * 8;         doff = WB_OFF + soff; }
    else if (gid < XN8 + WN8 + WoN8) { src = Wo; soff = (size_t)(gid - XN8 - WN8) * 8; doff = WOB_OFF + soff; }
    else return;
    const float4 a = *(const float4*)(src + soff);
    const float4 b = *(const float4*)(src + soff + 4);
    unsigned r0 = pack2(a.x, a.y), r1 = pack2(a.z, a.w);
    unsigned r2 = pack2(b.x, b.y), r3 = pack2(b.z, b.w);
    uint4 o; o.x = r0; o.y = r1; o.z = r2; o.w = r3;
    *(uint4*)(dst + doff) = o;
}

// ---------------------------------------------------------------------------
// Fused QKVG projection + attention per (b,h). Grid (BB, NH): b fast so the
// 4 h-siblings of a batch land on the SAME XCD (idx = b + 256h, mod 8 == b%8)
// and their 64-B og-line quarters merge in that XCD's L2 (round-2 evidence:
// WRITE_SIZE exactly 16 MiB with this order; 60 MiB with h-fast).
// 256 thr = 4 waves; wave w owns s/q rows [64w, 64w+64). 16x16x32 bf16 MFMA:
//   A/B-frag: row = lane&15, k = (lane>>4)*8 + j
//   C/D:      row = (lane>>4)*4 + reg, col = lane&15
// S^T = K·Q^T (softmax over k = per-lane regs + shfl_xor(16/32) over cols).
// P (C-layout, col q = l15) -> PV B-frag via cross-quad shuffles (no LDS).
// O^T = V^T·P^T.  LDS total 74.5 KB -> 2 blocks/CU.
// ---------------------------------------------------------------------------
__global__ __launch_bounds__(256, 2) void k_fused(
    const unsigned short* __restrict__ Xb,   // bf16 [B][S][128]
    const unsigned short* __restrict__ Wb,   // bf16 [512][128]
    const float* __restrict__ gbias,         // [128]
    const float* __restrict__ mask,          // [B][S] (k-indexed)
    const float* __restrict__ bias,          // [NH][S][S]
    unsigned short* __restrict__ og)         // bf16 ogT [S][B][128]
{
    const int b = blockIdx.x, h = blockIdx.y;
    const int t = threadIdx.x;
    const int w = t >> 6, lane = t & 63, l15 = lane & 15, quad = lane >> 4;

    __shared__ unsigned short Qb[SS * 40];   // [s][c] stride 40
    __shared__ unsigned short Kb[SS * 40];
    __shared__ unsigned short Vt[32 * 264];  // [c][s] stride 264
    __shared__ unsigned short Gb[SS * 34];   // [s][c] stride 34
    __shared__ float maskLds[SS];

    maskLds[t] = (mask[b * SS + t] - 1.0f) * 1e9f;

    const float qscale = 0.17677669529663687f;  // 1/sqrt(32)

    // ---------------- phase A: QKVG projection for head h ----------------
    for (int half = 0; half < 2; ++half) {
        bfrag Wfr[4][4];
#pragma unroll
        for (int f4 = 0; f4 < 4; ++f4) {
            const int floc = (half * 4 + f4) * 16 + l15;            // 0..127
            const int grow = (floc >> 5) * 128 + h * 32 + (floc & 31);
#pragma unroll
            for (int cc = 0; cc < 4; ++cc)
                Wfr[f4][cc] = *(const bfrag*)(Wb + grow * 128 + cc * 32 + quad * 8);
        }
#pragma unroll
        for (int st = 0; st < 4; ++st) {
            const int s = w * 64 + st * 16 + l15;
            bfrag Xfr[4];
#pragma unroll
            for (int cc = 0; cc < 4; ++cc)
                Xfr[cc] = *(const bfrag*)(Xb + (b * SS + s) * 128 + cc * 32 + quad * 8);
#pragma unroll
            for (int f4 = 0; f4 < 4; ++f4) {
                ffrag D = {0.f, 0.f, 0.f, 0.f};
#pragma unroll
                for (int cc = 0; cc < 4; ++cc)
                    D = __builtin_amdgcn_mfma_f32_16x16x32_bf16(Xfr[cc], Wfr[f4][cc], D, 0, 0, 0);
                const int ft = half * 4 + f4;
                const int fcol = ft * 16 + l15;
                const int srow0 = w * 64 + st * 16 + quad * 4;
                if (ft < 2) {
#pragma unroll
                    for (int r = 0; r < 4; ++r)
                        Qb[(srow0 + r) * 40 + fcol] = f2bf(D[r] * qscale);
                } else if (ft < 4) {
#pragma unroll
                    for (int r = 0; r < 4; ++r)
                        Kb[(srow0 + r) * 40 + (fcol - 32)] = f2bf(D[r]);
                } else if (ft < 6) {
                    const int base = (fcol - 64) * 264 + srow0;
                    *(unsigned*)&Vt[base]     = pack2(D[0], D[1]);
                    *(unsigned*)&Vt[base + 2] = pack2(D[2], D[3]);
                } else {
                    const int c = fcol - 96;
                    const float gb = gbias[h * 32 + c];
#pragma unroll
                    for (int r = 0; r < 4; ++r) {
                        const float g = 1.0f / (1.0f + __expf(-(D[r] + gb)));
                        Gb[(srow0 + r) * 34 + c] = f2bf(g);
                    }
                }
            }
        }
    }
    __syncthreads();

    // ---------------- phase B: attention ----------------
    bfrag Vfr[2][8];   // A-frags of V^T, loop-invariant
#pragma unroll
    for (int ch = 0; ch < 2; ++ch)
#pragma unroll
        for (int ck = 0; ck < 8; ++ck)
            Vfr[ch][ck] = *(const bfrag*)&Vt[(ch * 16 + l15) * 264 + ck * 32 + quad * 8];

    const int srcA = l15 + ((quad & 1) * 2) * 16;
    const int srcB = srcA + 16;
    const bool hi = (quad >> 1) != 0;

    for (int qq = 0; qq < 4; ++qq) {
        const int q = w * 64 + qq * 16 + l15;
        const bfrag Qfr = *(const bfrag*)&Qb[q * 40 + quad * 8];

        ffrag S[16];
#pragma unroll
        for (int kt = 0; kt < 16; ++kt) {
            const bfrag Kfr = *(const bfrag*)&Kb[(kt * 16 + l15) * 40 + quad * 8];
            const ffrag z = {0.f, 0.f, 0.f, 0.f};
            S[kt] = __builtin_amdgcn_mfma_f32_16x16x32_bf16(Kfr, Qfr, z, 0, 0, 0);
        }

        // + bias + mask; running max (lane owns column q; rows k=kt*16+quad*4+r)
        const float* brow = bias + (h * SS + q) * SS;
        float m = -1e30f;
#pragma unroll
        for (int kt = 0; kt < 16; ++kt) {
            const float4 bv = *(const float4*)(brow + kt * 16 + quad * 4);
            const float4 mv = *(const float4*)(maskLds + kt * 16 + quad * 4);
            S[kt][0] += bv.x + mv.x; S[kt][1] += bv.y + mv.y;
            S[kt][2] += bv.z + mv.z; S[kt][3] += bv.w + mv.w;
            m = fmaxf(m, fmaxf(fmaxf(S[kt][0], S[kt][1]), fmaxf(S[kt][2], S[kt][3])));
        }
        m = fmaxf(m, __shfl_xor(m, 16, 64));
        m = fmaxf(m, __shfl_xor(m, 32, 64));

        float l = 0.f;
        unsigned pk[16][2];   // P packed bf16 pairs (r01, r23), still C-layout
#pragma unroll
        for (int kt = 0; kt < 16; ++kt) {
            const float p0 = __expf(S[kt][0] - m);
            const float p1 = __expf(S[kt][1] - m);
            const float p2 = __expf(S[kt][2] - m);
            const float p3 = __expf(S[kt][3] - m);
            l += (p0 + p1) + (p2 + p3);
            pk[kt][0] = pack2(p0, p1);
            pk[kt][1] = pack2(p2, p3);
        }
        l += __shfl_xor(l, 16, 64);
        l += __shfl_xor(l, 32, 64);

        // C-layout -> B-frag transform via cross-quad shuffles.
        ffrag O[2];
        O[0] = (ffrag){0.f, 0.f, 0.f, 0.f};
        O[1] = (ffrag){0.f, 0.f, 0.f, 0.f};
#pragma unroll
        for (int ck = 0; ck < 8; ++ck) {
            const unsigned a0 = (unsigned)__shfl((int)pk[2 * ck][0],     srcA, 64);
            const unsigned b0 = (unsigned)__shfl((int)pk[2 * ck + 1][0], srcA, 64);
            const unsigned a1 = (unsigned)__shfl((int)pk[2 * ck][1],     srcA, 64);
            const unsigned b1 = (unsigned)__shfl((int)pk[2 * ck + 1][1], srcA, 64);
            const unsigned a2 = (unsigned)__shfl((int)pk[2 * ck][0],     srcB, 64);
            const unsigned b2 = (unsigned)__shfl((int)pk[2 * ck + 1][0], srcB, 64);
            const unsigned a3 = (unsigned)__shfl((int)pk[2 * ck][1],     srcB, 64);
            const unsigned b3 = (unsigned)__shfl((int)pk[2 * ck + 1][1], srcB, 64);
            FragU fu;
            fu.u[0] = hi ? b0 : a0;
            fu.u[1] = hi ? b1 : a1;
            fu.u[2] = hi ? b2 : a2;
            fu.u[3] = hi ? b3 : a3;
            O[0] = __builtin_amdgcn_mfma_f32_16x16x32_bf16(Vfr[0][ck], fu.b, O[0], 0, 0, 0);
            O[1] = __builtin_amdgcn_mfma_f32_16x16x32_bf16(Vfr[1][ck], fu.b, O[1], 0, 0, 0);
        }

        const float invl = 1.0f / l;
        const unsigned short* gr = &Gb[q * 34];
        // transposed og: ogT[q][b][128]
        unsigned* orow = (unsigned*)(og + ((size_t)q * BB + b) * 128 + h * 32);
#pragma unroll
        for (int ch = 0; ch < 2; ++ch) {
            const int c0 = ch * 16 + quad * 4;
            const float v0 = O[ch][0] * invl * bf2f(gr[c0 + 0]);
            const float v1 = O[ch][1] * invl * bf2f(gr[c0 + 1]);
            const float v2 = O[ch][2] * invl * bf2f(gr[c0 + 2]);
            const float v3 = O[ch][3] * invl * bf2f(gr[c0 + 3]);
            orow[(c0 >> 1) + 0] = pack2(v0, v1);
            orow[(c0 >> 1) + 1] = pack2(v2, v3);
        }
    }
}

// ---------------------------------------------------------------------------
// k3: out[i,j,c] = addt[i,j,c] + bo[c] + sum_f ogT[i][j][f] * Wo[c][f]
// Block (i, jt4): 64 j rows x all 128 c. ogT tile is a fully contiguous
// 16 KB chunk -> coalesced stage (64 B/thread). Wo held as per-wave register
// B-frags (wave w owns c in [32w, 32w+32)); each wave's two stores cover one
// full 128-B out line. LDS 17.4 KB, grid 1024 -> 4 blocks/CU.
// ---------------------------------------------------------------------------
__global__ __launch_bounds__(256, 4) void k3_proj(
    const unsigned short* __restrict__ ogb,  // bf16 ogT [S][B][128]
    const unsigned short* __restrict__ Wob,  // bf16 [128][128]
    const float* __restrict__ bo,            // [128]
    const float* __restrict__ addt,          // [S][B][128]
    float* __restrict__ out)                 // [S][B][128]
{
    const int i = blockIdx.x, jt4 = blockIdx.y;
    const int t = threadIdx.x;
    const int w = t >> 6, lane = t & 63, l15 = lane & 15, quad = lane >> 4;

    __shared__ unsigned short OgS[64 * 136];  // [j][f] stride 136

    // stage ogT[i][jt4*64 .. +64][0..128) -> LDS; contiguous 16 KB, 64 B/thr
    {
        const int jj = t >> 2, part = t & 3;
        const unsigned short* src = ogb + ((size_t)(i * BB + jt4 * 64 + jj) * 128) + part * 32;
        unsigned short* dst = &OgS[jj * 136 + part * 32];
        *(uint4*)(dst)      = *(const uint4*)(src);
        *(uint4*)(dst + 8)  = *(const uint4*)(src + 8);
        *(uint4*)(dst + 16) = *(const uint4*)(src + 16);
        *(uint4*)(dst + 24) = *(const uint4*)(src + 24);
    }

    // per-wave Wo B-frags: c rows (w*2+ctl)*16 + l15
    bfrag Wfr[2][4];
#pragma unroll
    for (int ctl = 0; ctl < 2; ++ctl) {
        const int crow = (w * 2 + ctl) * 16 + l15;
#pragma unroll
        for (int cc = 0; cc < 4; ++cc)
            Wfr[ctl][cc] = *(const bfrag*)(Wob + crow * 128 + cc * 32 + quad * 8);
    }
    const float bo0 = bo[(w * 2 + 0) * 16 + l15];
    const float bo1 = bo[(w * 2 + 1) * 16 + l15];

    __syncthreads();

#pragma unroll
    for (int jt = 0; jt < 4; ++jt) {
        bfrag Ab[4];
#pragma unroll
        for (int cc = 0; cc < 4; ++cc)
            Ab[cc] = *(const bfrag*)&OgS[(jt * 16 + l15) * 136 + cc * 32 + quad * 8];

        ffrag D0 = {0.f, 0.f, 0.f, 0.f};
        ffrag D1 = {0.f, 0.f, 0.f, 0.f};
#pragma unroll
        for (int cc = 0; cc < 4; ++cc) {
            D0 = __builtin_amdgcn_mfma_f32_16x16x32_bf16(Ab[cc], Wfr[0][cc], D0, 0, 0, 0);
            D1 = __builtin_amdgcn_mfma_f32_16x16x32_bf16(Ab[cc], Wfr[1][cc], D1, 0, 0, 0);
        }

        const int c0 = (w * 2 + 0) * 16 + l15;
        const int c1 = (w * 2 + 1) * 16 + l15;
#pragma unroll
        for (int r = 0; r < 4; ++r) {
            const int j = jt4 * 64 + jt * 16 + quad * 4 + r;
            const size_t row = (size_t)(i * BB + j) * 128;
            out[row + c0] = D0[r] + bo0 + addt[row + c0];
            out[row + c1] = D1[r] + bo1 + addt[row + c1];
        }
    }
}

extern "C" void kernel_launch(void* const* d_in, const int* in_sizes, int n_in,
                              void* d_out, int out_size, void* d_ws, size_t ws_size,
                              hipStream_t stream) {
    const float* X     = (const float*)d_in[0];  // input_qkv [1,256,256,128]
    const float* mask  = (const float*)d_in[1];  // [1,256,1,1,256]
    const float* bias  = (const float*)d_in[2];  // [1,1,4,256,256]
    const float* addt  = (const float*)d_in[3];  // [1,256,256,128]
    const float* Wqkvg = (const float*)d_in[4];  // [512,128]
    const float* gbias = (const float*)d_in[5];  // [128]
    const float* Wo    = (const float*)d_in[6];  // [128,128]
    const float* bo    = (const float*)d_in[7];  // [128]
    float* out = (float*)d_out;

    unsigned short* ws = (unsigned short*)d_ws;
    unsigned short* Xb  = ws + XB_OFF;
    unsigned short* Wb  = ws + WB_OFF;
    unsigned short* Wob = ws + WOB_OFF;
    unsigned short* og  = ws + OG_OFF;

    k0_cast<<<4136, 256, 0, stream>>>(X, Wqkvg, Wo, ws);
    k_fused<<<dim3(BB, NH), 256, 0, stream>>>(Xb, Wb, gbias, mask, bias, og);
    k3_proj<<<dim3(SS, 4), 256, 0, stream>>>(og, Wob, bo, addt, out);
}